// Round 6
// baseline (927.021 us; speedup 1.0000x reference)
//
#include <hip/hip_runtime.h>
#include <hip/hip_fp16.h>
#include <math.h>

#define NH 5
#define NC 64
#define ED 16
#define HC 320   // NH*NC
#define CH 32    // CSR slots per wave window in gat_fused

typedef _Float16 h2  __attribute__((ext_vector_type(2)));
typedef _Float16 v4h __attribute__((ext_vector_type(4)));
typedef _Float16 v8h __attribute__((ext_vector_type(8)));
typedef float    v4f __attribute__((ext_vector_type(4)));

// ---------------- wave64 sum via single-instruction DPP adds ----------------
__device__ __forceinline__ float wave_sum_all(float x) {
    asm("v_add_f32_dpp %0, %1, %0 quad_perm:[1,0,3,2] row_mask:0xf bank_mask:0xf"
        : "+v"(x) : "v"(x));
    asm("v_add_f32_dpp %0, %1, %0 quad_perm:[2,3,0,1] row_mask:0xf bank_mask:0xf"
        : "+v"(x) : "v"(x));
    asm("v_add_f32_dpp %0, %1, %0 row_half_mirror row_mask:0xf bank_mask:0xf"
        : "+v"(x) : "v"(x));
    asm("v_add_f32_dpp %0, %1, %0 row_mirror row_mask:0xf bank_mask:0xf"
        : "+v"(x) : "v"(x));
    asm("v_add_f32_dpp %0, %1, %0 row_bcast:15 row_mask:0xa bank_mask:0xf"
        : "+v"(x) : "v"(x));
    asm("v_add_f32_dpp %0, %1, %0 row_bcast:31 row_mask:0xc bank_mask:0xf"
        : "+v"(x) : "v"(x));
    return __int_as_float(__builtin_amdgcn_readlane(__float_as_int(x), 63));
}

// ---------------- preprocessing ----------------

__global__ void count_kernel(const int* __restrict__ dst, int* __restrict__ cnt, int E) {
    int t = blockIdx.x * blockDim.x + threadIdx.x;
    if (t >= E) return;
    atomicAdd(&cnt[dst[t]], 1);
}

__global__ void scan_kernel(const int* __restrict__ cnt, int* __restrict__ offsets,
                            int* __restrict__ cursor, int N) {
    __shared__ int sums[1024];
    int t = threadIdx.x;
    int chunk = (N + 1023) / 1024;
    int beg = t * chunk;
    int end = min(beg + chunk, N);
    int s = 0;
    for (int i = beg; i < end; ++i) s += cnt[i] + 1;
    sums[t] = s;
    __syncthreads();
    for (int o = 1; o < 1024; o <<= 1) {
        int v = (t >= o) ? sums[t - o] : 0;
        __syncthreads();
        sums[t] += v;
        __syncthreads();
    }
    int run = (t > 0) ? sums[t - 1] : 0;
    for (int i = beg; i < end; ++i) {
        offsets[i] = run; cursor[i] = run;
        run += cnt[i] + 1;
    }
    if (t == 0) offsets[N] = sums[1023];
}

__global__ void scatter_kernel(const int* __restrict__ src, const int* __restrict__ dst,
                               int* __restrict__ cursor, int2* __restrict__ recs, int N, int E) {
    int t = blockIdx.x * blockDim.x + threadIdx.x;
    if (t >= E + N) return;
    int d, s;
    if (t < E) { d = dst[t]; s = src[t]; }
    else       { d = t - E; s = t - E; }
    int pos = atomicAdd(&cursor[d], 1);
    recs[pos] = make_int2(s, t);
}

__global__ void loop_from_csr(const int* __restrict__ offsets, const int2* __restrict__ recs,
                              const float* __restrict__ ea, float* __restrict__ loop,
                              int N, int E) {
    int t = blockIdx.x * blockDim.x + threadIdx.x;
    int n = t >> 4, k = t & 15;
    if (n >= N) return;
    int beg = offsets[n], end = offsets[n + 1];
    float s = 0.f; int c = 0;
    for (int j = beg; j < end; ++j) {
        int y = recs[j].y;
        if (y < E) { s += ea[(size_t)y * ED + k]; ++c; }
    }
    loop[(size_t)n * ED + k] = s / (float)max(c, 1);
}

// also extracts srcs[] so the fused kernel never touches recs (int2)
__global__ void reorder_ea(const int2* __restrict__ recs, const float* __restrict__ ea,
                           const float* __restrict__ loop, h2* __restrict__ easrt,
                           int* __restrict__ srcs, int R, int E) {
    int t = blockIdx.x * blockDim.x + threadIdx.x;
    int slot = t >> 3, k2 = t & 7;
    if (slot >= R) return;
    int2 rc = recs[slot];
    if (k2 == 0) srcs[slot] = rc.x;
    int y = rc.y;
    const float2* sp = (const float2*)((y < E) ? ea + (size_t)y * ED : loop + (size_t)(y - E) * ED);
    float2 f = sp[k2];
    h2 o; o.x = (_Float16)f.x; o.y = (_Float16)f.y;
    easrt[(size_t)slot * 8 + k2] = o;
}

// window -> first node starting in it (atomicMin; sentinel 0x7f7f7f7f)
__global__ void win_start_kernel(const int* __restrict__ offsets, int* __restrict__ winStart, int N) {
    int i = blockIdx.x * blockDim.x + threadIdx.x;
    if (i >= N) return;
    atomicMin(&winStart[offsets[i] / CH], i);
}

// fp32 -> fp16 elementwise
__global__ void cvt_f16(const float* __restrict__ in, _Float16* __restrict__ out, int n) {
    int i = blockIdx.x * blockDim.x + threadIdx.x;
    if (i < n) out[i] = (_Float16)in[i];
}

// W[K][320] -> Wt[320][K] fp16
__global__ void transpose_w(const float* __restrict__ W, _Float16* __restrict__ Wt, int K) {
    int t = blockIdx.x * blockDim.x + threadIdx.x;
    if (t >= 320 * K) return;
    int k = t / 320, n = t % 320;
    Wt[(size_t)n * K + k] = (_Float16)W[t];
}

// ---------------- MFMA GEMM: C = Ah[M,K] @ Wt[320,K]^T + bias ----------------
// Split output: CoutA[row][64][4] = heads 0..3, CoutB[row][64] = head 4. 640 B/row.
__global__ __launch_bounds__(256) void gemm_mfma(const _Float16* __restrict__ A,
                                                 const _Float16* __restrict__ Bt,
                                                 const float* __restrict__ bias,
                                                 _Float16* __restrict__ CoutA,
                                                 _Float16* __restrict__ CoutB, int M, int K) {
    int lane = threadIdx.x & 63;
    int wave = threadIdx.x >> 6;
    int m = lane & 15, quad = lane >> 4;
    int rowBase = (blockIdx.x * 4 + wave) * 16;
    if (rowBase >= M) return;

    v4f acc[20];
#pragma unroll
    for (int c = 0; c < 20; ++c) acc[c] = (v4f){0.f, 0.f, 0.f, 0.f};

    for (int k0 = 0; k0 < K; k0 += 32) {
        v8h a = *(const v8h*)&A[(size_t)(rowBase + m) * K + k0 + quad * 8];
#pragma unroll
        for (int c = 0; c < 20; ++c) {
            v8h b = *(const v8h*)&Bt[(size_t)(c * 16 + m) * K + k0 + quad * 8];
            acc[c] = __builtin_amdgcn_mfma_f32_16x16x32_f16(a, b, acc[c], 0, 0, 0);
        }
    }
    float bb[20];
#pragma unroll
    for (int c = 0; c < 20; ++c) bb[c] = bias[c * 16 + m];
#pragma unroll
    for (int r = 0; r < 4; ++r) {
        int row = rowBase + quad * 4 + r;
#pragma unroll
        for (int c03 = 0; c03 < 4; ++c03) {
            v4h o;
#pragma unroll
            for (int h = 0; h < 4; ++h) {
                int c = c03 + 4 * h;
                o[h] = (_Float16)(acc[c][r] + bb[c]);
            }
            int cw = c03 * 16 + m;
            *(v4h*)&CoutA[(((size_t)row) * 64 + cw) * 4] = o;
            int c4 = c03 + 16;                  // head 4
            CoutB[((size_t)row) * 64 + cw] = (_Float16)(acc[c4][r] + bb[c4]);
        }
    }
}

// ---------------- fused logits + single-pass softmax + aggregate + ELU ----------------
// Proven 2-edge structure (round-3 numerics) + explicit 2-stage software pipeline:
// next pair's gathers issue BEFORE current pair's fdot2/reduce, hiding L2/L3
// gather latency under ~300-400 cyc of compute. Guarded -> no OOB speculation.
__global__ __launch_bounds__(256) void gat_fused(const _Float16* __restrict__ hA,
                                                 const _Float16* __restrict__ hB,
                                                 const int* __restrict__ offsets,
                                                 const int* __restrict__ srcs,
                                                 const h2* __restrict__ easrt,
                                                 const int* __restrict__ winStart,
                                                 const float* __restrict__ We,
                                                 const float* __restrict__ att,
                                                 const float* __restrict__ bias,
                                                 _Float16* __restrict__ outH,
                                                 float* __restrict__ outF,
                                                 int N, int R) {
    int lane = threadIdx.x & 63;
    int wave = (blockIdx.x * blockDim.x + threadIdx.x) >> 6;
    int totalWaves = (gridDim.x * blockDim.x) >> 6;
    const float L2E = 1.4426950408889634f;   // fold log2(e) into att -> native v_exp (exp2)

    h2 we2[8 * NH];
#pragma unroll
    for (int k2 = 0; k2 < 8; ++k2)
#pragma unroll
        for (int h = 0; h < NH; ++h) {
            h2 w;
            w.x = (_Float16)We[(2 * k2) * HC + h * NC + lane];
            w.y = (_Float16)We[(2 * k2 + 1) * HC + h * NC + lane];
            we2[k2 * NH + h] = w;
        }
    float attc6[NH], attc4[NH];
#pragma unroll
    for (int h = 0; h < NH; ++h) {
        float a = att[h * NC + lane];
        attc6[h] = 0.6f * L2E * a;
        attc4[h] = 0.4f * L2E * a;
    }
    float bc = bias[lane];

    for (int w = wave; w * CH < R; w += totalWaves) {
        int i = winStart[w];
        if (i >= N) continue;
        int winEnd = w * CH + CH;
        for (; i < N; ++i) {
            int beg = offsets[i];
            if (beg >= winEnd) break;
            int end = offsets[i + 1];

            v4h hd4 = *(const v4h*)&hA[((size_t)i * 64 + lane) * 4];
            float hd[NH];
#pragma unroll
            for (int h = 0; h < 4; ++h) hd[h] = (float)hd4[h];
            hd[4] = (float)hB[(size_t)i * 64 + lane];

            float l[NH] = {}, acc[NH] = {};
            int t = beg;
            int npairs = (end - t) >> 1;
            if (npairs > 0) {
                // ---- prologue: load pair 0 ----
                int s0 = srcs[t], s1 = srcs[t + 1];
                v4h c0 = *(const v4h*)&hA[((size_t)s0 * 64 + lane) * 4];
                v4h c1 = *(const v4h*)&hA[((size_t)s1 * 64 + lane) * 4];
                _Float16 ce0 = hB[(size_t)s0 * 64 + lane];
                _Float16 ce1 = hB[(size_t)s1 * 64 + lane];
                h2 ca0[8], ca1[8];
                {
                    const h2* ap = easrt + (size_t)t * 8;
#pragma unroll
                    for (int k2 = 0; k2 < 8; ++k2) { ca0[k2] = ap[k2]; ca1[k2] = ap[8 + k2]; }
                }
                for (int pp = 0; pp < npairs; ++pp) {
                    int tn = t + 2;
                    // ---- issue next pair's loads before current compute ----
                    v4h n0v = {}, n1v = {};
                    _Float16 n0e = (_Float16)0.f, n1e = (_Float16)0.f;
                    h2 na0[8] = {}, na1[8] = {};
                    if (pp + 1 < npairs) {
                        int ns0 = srcs[tn], ns1 = srcs[tn + 1];
                        n0v = *(const v4h*)&hA[((size_t)ns0 * 64 + lane) * 4];
                        n1v = *(const v4h*)&hA[((size_t)ns1 * 64 + lane) * 4];
                        n0e = hB[(size_t)ns0 * 64 + lane];
                        n1e = hB[(size_t)ns1 * 64 + lane];
                        const h2* ap = easrt + (size_t)tn * 8;
#pragma unroll
                        for (int k2 = 0; k2 < 8; ++k2) { na0[k2] = ap[k2]; na1[k2] = ap[8 + k2]; }
                    }
                    // ---- compute current pair (round-3 proven numerics) ----
                    float hs0[NH], hs1[NH], p0[NH], p1[NH];
#pragma unroll
                    for (int h = 0; h < 4; ++h) { hs0[h] = (float)c0[h]; hs1[h] = (float)c1[h]; }
                    hs0[4] = (float)ce0; hs1[4] = (float)ce1;
#pragma unroll
                    for (int h = 0; h < NH; ++h) {
                        float v0 = hs0[h] + hd[h];
                        float v1 = hs1[h] + hd[h];
#pragma unroll
                        for (int k2 = 0; k2 < 8; ++k2) {
                            v0 = __builtin_amdgcn_fdot2(ca0[k2], we2[k2 * NH + h], v0, false);
                            v1 = __builtin_amdgcn_fdot2(ca1[k2], we2[k2 * NH + h], v1, false);
                        }
                        p0[h] = fmaf(fabsf(v0), attc4[h], v0 * attc6[h]);
                        p1[h] = fmaf(fabsf(v1), attc4[h], v1 * attc6[h]);
                    }
#pragma unroll
                    for (int h = 0; h < NH; ++h) {
                        float pe0 = exp2f(wave_sum_all(p0[h]));
                        float pe1 = exp2f(wave_sum_all(p1[h]));
                        l[h] += pe0 + pe1;
                        acc[h] = fmaf(pe0, hs0[h], fmaf(pe1, hs1[h], acc[h]));
                    }
                    // ---- rotate next -> current ----
                    c0 = n0v; c1 = n1v; ce0 = n0e; ce1 = n1e;
#pragma unroll
                    for (int k2 = 0; k2 < 8; ++k2) { ca0[k2] = na0[k2]; ca1[k2] = na1[k2]; }
                    t = tn;
                }
            }
            // ---- 1-edge tail ----
            if (t < end) {
                int s0 = srcs[t];
                v4h hs0v = *(const v4h*)&hA[((size_t)s0 * 64 + lane) * 4];
                _Float16 hs0e = hB[(size_t)s0 * 64 + lane];
                const h2* ap = easrt + (size_t)t * 8;
                h2 a0[8];
#pragma unroll
                for (int k2 = 0; k2 < 8; ++k2) a0[k2] = ap[k2];
                float hs0[NH];
#pragma unroll
                for (int h = 0; h < 4; ++h) hs0[h] = (float)hs0v[h];
                hs0[4] = (float)hs0e;
#pragma unroll
                for (int h = 0; h < NH; ++h) {
                    float v0 = hs0[h] + hd[h];
#pragma unroll
                    for (int k2 = 0; k2 < 8; ++k2)
                        v0 = __builtin_amdgcn_fdot2(a0[k2], we2[k2 * NH + h], v0, false);
                    float pe0 = exp2f(wave_sum_all(fmaf(fabsf(v0), attc4[h], v0 * attc6[h])));
                    l[h] += pe0;
                    acc[h] = fmaf(pe0, hs0[h], acc[h]);
                }
            }
            float o = 0.f;
#pragma unroll
            for (int h = 0; h < NH; ++h) o += acc[h] / l[h];
            o = o * 0.2f + bc;
            o = o > 0.f ? o : expm1f(o);
            if (outF) outF[(size_t)i * NC + lane] = o;
            else      outH[(size_t)i * NC + lane] = (_Float16)o;
        }
    }
}

// ---------------- launch ----------------
extern "C" void kernel_launch(void* const* d_in, const int* in_sizes, int n_in,
                              void* d_out, int out_size, void* d_ws, size_t ws_size,
                              hipStream_t stream) {
    const float* x     = (const float*)d_in[0];
    const int*   ei    = (const int*)d_in[1];
    const float* ea    = (const float*)d_in[2];
    const float* W0    = (const float*)d_in[3];
    const float* b0    = (const float*)d_in[4];
    const float* We0   = (const float*)d_in[5];
    const float* att0  = (const float*)d_in[6];
    const float* bias0 = (const float*)d_in[7];
    const float* W12   = (const float*)d_in[8];
    const float* b12   = (const float*)d_in[9];
    const float* We12  = (const float*)d_in[10];
    const float* att12 = (const float*)d_in[11];
    const float* bias12= (const float*)d_in[12];

    int N = in_sizes[0] / 128;
    int E = in_sizes[1] / 2;
    int R = E + N;
    int numWin = (R + CH - 1) / CH;
    const int* srcArr = ei;
    const int* dstArr = ei + E;

    char* ws = (char*)d_ws;
    size_t off = 0;
    auto alloc = [&](size_t bytes) -> void* {
        void* p = ws + off;
        off = (off + bytes + 255) & ~(size_t)255;
        return p;
    };
    int*      cnt     = (int*)alloc((size_t)N * 4);
    int*      offsets = (int*)alloc((size_t)(N + 1) * 4);
    int*      cursor  = (int*)alloc((size_t)N * 4);
    int2*     recs    = (int2*)alloc((size_t)R * 8);
    float*    loop    = (float*)alloc((size_t)N * ED * 4);
    _Float16* hbufA   = (_Float16*)alloc((size_t)N * 64 * 4 * 2); // [N][64][4] heads 0-3
    _Float16* hbufB   = (_Float16*)alloc((size_t)N * 64 * 2);     // [N][64]    head 4
    _Float16* acth    = (_Float16*)alloc((size_t)N * NC * 2);
    _Float16* xh      = (_Float16*)alloc((size_t)N * 128 * 2);
    _Float16* Wth0    = (_Float16*)alloc((size_t)320 * 128 * 2);
    _Float16* Wth1    = (_Float16*)alloc((size_t)320 * 64 * 2);
    _Float16* Wth2    = (_Float16*)alloc((size_t)320 * 64 * 2);
    int*      winStart= (int*)alloc((size_t)(numWin + 1) * 4);
    h2*       easrt   = (h2*)alloc((size_t)R * 32);
    int*      srcs    = (int*)alloc((size_t)R * 4);

    (void)hipMemsetAsync(cnt, 0, (size_t)N * 4, stream);
    (void)hipMemsetAsync(winStart, 0x7f, (size_t)(numWin + 1) * 4, stream);
    count_kernel<<<(E + 255) / 256, 256, 0, stream>>>(dstArr, cnt, E);
    scan_kernel<<<1, 1024, 0, stream>>>(cnt, offsets, cursor, N);
    scatter_kernel<<<(E + N + 255) / 256, 256, 0, stream>>>(srcArr, dstArr, cursor, recs, N, E);
    loop_from_csr<<<((size_t)N * ED + 255) / 256, 256, 0, stream>>>(offsets, recs, ea, loop, N, E);
    reorder_ea<<<((size_t)R * 8 + 255) / 256, 256, 0, stream>>>(recs, ea, loop, easrt, srcs, R, E);
    win_start_kernel<<<(N + 255) / 256, 256, 0, stream>>>(offsets, winStart, N);
    cvt_f16<<<((size_t)N * 128 + 255) / 256, 256, 0, stream>>>(x, xh, N * 128);
    transpose_w<<<(320 * 128 + 255) / 256, 256, 0, stream>>>(W0, Wth0, 128);
    transpose_w<<<(320 * 64 + 255) / 256, 256, 0, stream>>>(W12, Wth1, 64);
    transpose_w<<<(320 * 64 + 255) / 256, 256, 0, stream>>>(W12 + 64 * HC, Wth2, 64);

    float* dout = (float*)d_out;
    int gemmBlocks = (N / 16 + 3) / 4 + 1;
    int fusedBlocks = (numWin + 3) / 4;   // one window per wave

    const _Float16* As[3]  = {xh, acth, acth};
    const _Float16* Bts[3] = {Wth0, Wth1, Wth2};
    int Ks[3] = {128, 64, 64};
    const float* bs[3]   = {b0, b12, b12 + HC};
    const float* Wes[3]  = {We0, We12, We12 + ED * HC};
    const float* atts[3] = {att0, att12, att12 + NH * NC};
    const float* bis[3]  = {bias0, bias12, bias12 + NC};
    for (int layer = 0; layer < 3; ++layer) {
        gemm_mfma<<<gemmBlocks, 256, 0, stream>>>(As[layer], Bts[layer], bs[layer],
                                                  hbufA, hbufB, N, Ks[layer]);
        gat_fused<<<fusedBlocks, 256, 0, stream>>>(hbufA, hbufB, offsets, srcs, easrt, winStart,
                                                   Wes[layer], atts[layer], bis[layer],
                                                   acth, (layer == 2) ? dout : nullptr, N, R);
    }
}

// Round 7
// 821.726 us; speedup vs baseline: 1.1281x; 1.1281x over previous
//
#include <hip/hip_runtime.h>
#include <hip/hip_fp16.h>
#include <math.h>

#define NH 5
#define NC 64
#define ED 16
#define HC 320   // NH*NC
#define CH 32    // CSR slots per wave window in gat_fused

typedef _Float16 h2  __attribute__((ext_vector_type(2)));
typedef _Float16 v4h __attribute__((ext_vector_type(4)));
typedef _Float16 v8h __attribute__((ext_vector_type(8)));
typedef float    v4f __attribute__((ext_vector_type(4)));

// ---------------- wave64 sum via single-instruction DPP adds ----------------
// 10-chain interleave proven across 3 passing runs; do NOT widen (R5: 20 chains
// exposed the DPP read-after-VALU-write hazard the compiler can't see in asm).
__device__ __forceinline__ float wave_sum_all(float x) {
    asm("v_add_f32_dpp %0, %1, %0 quad_perm:[1,0,3,2] row_mask:0xf bank_mask:0xf"
        : "+v"(x) : "v"(x));
    asm("v_add_f32_dpp %0, %1, %0 quad_perm:[2,3,0,1] row_mask:0xf bank_mask:0xf"
        : "+v"(x) : "v"(x));
    asm("v_add_f32_dpp %0, %1, %0 row_half_mirror row_mask:0xf bank_mask:0xf"
        : "+v"(x) : "v"(x));
    asm("v_add_f32_dpp %0, %1, %0 row_mirror row_mask:0xf bank_mask:0xf"
        : "+v"(x) : "v"(x));
    asm("v_add_f32_dpp %0, %1, %0 row_bcast:15 row_mask:0xa bank_mask:0xf"
        : "+v"(x) : "v"(x));
    asm("v_add_f32_dpp %0, %1, %0 row_bcast:31 row_mask:0xc bank_mask:0xf"
        : "+v"(x) : "v"(x));
    return __int_as_float(__builtin_amdgcn_readlane(__float_as_int(x), 63));
}

// ---------------- preprocessing ----------------

__global__ void count_kernel(const int* __restrict__ dst, int* __restrict__ cnt, int E) {
    int t = blockIdx.x * blockDim.x + threadIdx.x;
    if (t >= E) return;
    atomicAdd(&cnt[dst[t]], 1);
}

__global__ void scan_kernel(const int* __restrict__ cnt, int* __restrict__ offsets,
                            int* __restrict__ cursor, int N) {
    __shared__ int sums[1024];
    int t = threadIdx.x;
    int chunk = (N + 1023) / 1024;
    int beg = t * chunk;
    int end = min(beg + chunk, N);
    int s = 0;
    for (int i = beg; i < end; ++i) s += cnt[i] + 1;
    sums[t] = s;
    __syncthreads();
    for (int o = 1; o < 1024; o <<= 1) {
        int v = (t >= o) ? sums[t - o] : 0;
        __syncthreads();
        sums[t] += v;
        __syncthreads();
    }
    int run = (t > 0) ? sums[t - 1] : 0;
    for (int i = beg; i < end; ++i) {
        offsets[i] = run; cursor[i] = run;
        run += cnt[i] + 1;
    }
    if (t == 0) offsets[N] = sums[1023];
}

// also records each node's self-loop slot so loop_fill can target it directly
__global__ void scatter_kernel(const int* __restrict__ src, const int* __restrict__ dst,
                               int* __restrict__ cursor, int2* __restrict__ recs,
                               int* __restrict__ selfSlot, int N, int E) {
    int t = blockIdx.x * blockDim.x + threadIdx.x;
    if (t >= E + N) return;
    int d, s;
    if (t < E) { d = dst[t]; s = src[t]; }
    else       { d = t - E; s = t - E; }
    int pos = atomicAdd(&cursor[d], 1);
    recs[pos] = make_int2(s, t);
    if (t >= E) selfSlot[d] = pos;
}

// real-edge slots: gather ea row -> fp16 easrt; self slots left for loop_fill.
// also extracts srcs[] so the fused kernel never touches recs (int2)
__global__ void reorder_ea(const int2* __restrict__ recs, const float* __restrict__ ea,
                           h2* __restrict__ easrt, int* __restrict__ srcs, int R, int E) {
    int t = blockIdx.x * blockDim.x + threadIdx.x;
    int slot = t >> 3, k2 = t & 7;
    if (slot >= R) return;
    int2 rc = recs[slot];
    if (k2 == 0) srcs[slot] = rc.x;
    int y = rc.y;
    if (y >= E) return;                      // self slot: filled by loop_fill
    const float2* sp = (const float2*)(ea + (size_t)y * ED);
    float2 f = sp[k2];
    h2 o; o.x = (_Float16)f.x; o.y = (_Float16)f.y;
    easrt[(size_t)slot * 8 + k2] = o;
}

// self-loop attr = mean of the segment's real-edge attrs, read SEQUENTIALLY
// from easrt (replaces loop_from_csr's 16x-redundant recs reads + 2nd ea gather)
__global__ void loop_fill(const int* __restrict__ offsets, const int* __restrict__ selfSlot,
                          h2* __restrict__ easrt, int N) {
    int t = blockIdx.x * blockDim.x + threadIdx.x;
    int n = t >> 3, k2 = t & 7;
    if (n >= N) return;
    int beg = offsets[n], end = offsets[n + 1];
    int ss = selfSlot[n];
    float sx = 0.f, sy = 0.f;
    for (int j = beg; j < end; ++j) {
        if (j == ss) continue;
        h2 v = easrt[(size_t)j * 8 + k2];
        sx += (float)v.x; sy += (float)v.y;
    }
    float inv = 1.f / (float)max(end - beg - 1, 1);
    h2 o; o.x = (_Float16)(sx * inv); o.y = (_Float16)(sy * inv);
    easrt[(size_t)ss * 8 + k2] = o;
}

// window -> first node starting in it (atomicMin; sentinel 0x7f7f7f7f)
__global__ void win_start_kernel(const int* __restrict__ offsets, int* __restrict__ winStart, int N) {
    int i = blockIdx.x * blockDim.x + threadIdx.x;
    if (i >= N) return;
    atomicMin(&winStart[offsets[i] / CH], i);
}

// W[K][320] -> Wt[320][K] fp16
__global__ void transpose_w(const float* __restrict__ W, _Float16* __restrict__ Wt, int K) {
    int t = blockIdx.x * blockDim.x + threadIdx.x;
    if (t >= 320 * K) return;
    int k = t / 320, n = t % 320;
    Wt[(size_t)n * K + k] = (_Float16)W[t];
}

// ---------------- MFMA GEMM: C = A[M,K] @ Wt[320,K]^T + bias ----------------
// A either fp16 (Ah) or fp32 (Af, converted in-register: layer 0 reads x
// directly, killing the cvt_f16 kernel + 38 MB xh round-trip).
// Split output: CoutA[row][64][4] = heads 0..3, CoutB[row][64] = head 4. 640 B/row.
__global__ __launch_bounds__(256) void gemm_mfma(const _Float16* __restrict__ Ah,
                                                 const float* __restrict__ Af,
                                                 const _Float16* __restrict__ Bt,
                                                 const float* __restrict__ bias,
                                                 _Float16* __restrict__ CoutA,
                                                 _Float16* __restrict__ CoutB, int M, int K) {
    int lane = threadIdx.x & 63;
    int wave = threadIdx.x >> 6;
    int m = lane & 15, quad = lane >> 4;
    int rowBase = (blockIdx.x * 4 + wave) * 16;
    if (rowBase >= M) return;

    v4f acc[20];
#pragma unroll
    for (int c = 0; c < 20; ++c) acc[c] = (v4f){0.f, 0.f, 0.f, 0.f};

    for (int k0 = 0; k0 < K; k0 += 32) {
        v8h a;
        if (Af) {
            const float* ap = &Af[(size_t)(rowBase + m) * K + k0 + quad * 8];
            float4 f0 = *(const float4*)ap;
            float4 f1 = *(const float4*)(ap + 4);
            a[0] = (_Float16)f0.x; a[1] = (_Float16)f0.y;
            a[2] = (_Float16)f0.z; a[3] = (_Float16)f0.w;
            a[4] = (_Float16)f1.x; a[5] = (_Float16)f1.y;
            a[6] = (_Float16)f1.z; a[7] = (_Float16)f1.w;
        } else {
            a = *(const v8h*)&Ah[(size_t)(rowBase + m) * K + k0 + quad * 8];
        }
#pragma unroll
        for (int c = 0; c < 20; ++c) {
            v8h b = *(const v8h*)&Bt[(size_t)(c * 16 + m) * K + k0 + quad * 8];
            acc[c] = __builtin_amdgcn_mfma_f32_16x16x32_f16(a, b, acc[c], 0, 0, 0);
        }
    }
    float bb[20];
#pragma unroll
    for (int c = 0; c < 20; ++c) bb[c] = bias[c * 16 + m];
#pragma unroll
    for (int r = 0; r < 4; ++r) {
        int row = rowBase + quad * 4 + r;
#pragma unroll
        for (int c03 = 0; c03 < 4; ++c03) {
            v4h o;
#pragma unroll
            for (int h = 0; h < 4; ++h) {
                int c = c03 + 4 * h;
                o[h] = (_Float16)(acc[c][r] + bb[c]);
            }
            int cw = c03 * 16 + m;
            *(v4h*)&CoutA[(((size_t)row) * 64 + cw) * 4] = o;
            int c4 = c03 + 16;                  // head 4
            CoutB[((size_t)row) * 64 + cw] = (_Float16)(acc[c4][r] + bb[c4]);
        }
    }
}

// ---------------- fused logits + single-pass softmax + aggregate + ELU ----------------
// Round-3 proven structure (162 us) + s_setprio(1) around the compute cluster
// (independent waves, no barriers -> the attn-positive setprio regime).
__global__ __launch_bounds__(256) void gat_fused(const _Float16* __restrict__ hA,
                                                 const _Float16* __restrict__ hB,
                                                 const int* __restrict__ offsets,
                                                 const int* __restrict__ srcs,
                                                 const h2* __restrict__ easrt,
                                                 const int* __restrict__ winStart,
                                                 const float* __restrict__ We,
                                                 const float* __restrict__ att,
                                                 const float* __restrict__ bias,
                                                 _Float16* __restrict__ outH,
                                                 float* __restrict__ outF,
                                                 int N, int R) {
    int lane = threadIdx.x & 63;
    int wave = (blockIdx.x * blockDim.x + threadIdx.x) >> 6;
    int totalWaves = (gridDim.x * blockDim.x) >> 6;
    const float L2E = 1.4426950408889634f;   // fold log2(e) into att -> native v_exp (exp2)

    h2 we2[8 * NH];
#pragma unroll
    for (int k2 = 0; k2 < 8; ++k2)
#pragma unroll
        for (int h = 0; h < NH; ++h) {
            h2 w;
            w.x = (_Float16)We[(2 * k2) * HC + h * NC + lane];
            w.y = (_Float16)We[(2 * k2 + 1) * HC + h * NC + lane];
            we2[k2 * NH + h] = w;
        }
    float attc6[NH], attc4[NH];
#pragma unroll
    for (int h = 0; h < NH; ++h) {
        float a = att[h * NC + lane];
        attc6[h] = 0.6f * L2E * a;
        attc4[h] = 0.4f * L2E * a;
    }
    float bc = bias[lane];

    for (int w = wave; w * CH < R; w += totalWaves) {
        int i = winStart[w];
        if (i >= N) continue;
        int winEnd = w * CH + CH;
        for (; i < N; ++i) {
            int beg = offsets[i];
            if (beg >= winEnd) break;
            int end = offsets[i + 1];

            v4h hd4 = *(const v4h*)&hA[((size_t)i * 64 + lane) * 4];
            float hd[NH];
#pragma unroll
            for (int h = 0; h < 4; ++h) hd[h] = (float)hd4[h];
            hd[4] = (float)hB[(size_t)i * 64 + lane];

            float l[NH] = {}, acc[NH] = {};
            int t = beg;
            for (; t + 2 <= end; t += 2) {
                int s0 = srcs[t], s1 = srcs[t + 1];
                v4h hs0v = *(const v4h*)&hA[((size_t)s0 * 64 + lane) * 4];
                v4h hs1v = *(const v4h*)&hA[((size_t)s1 * 64 + lane) * 4];
                _Float16 hs0e = hB[(size_t)s0 * 64 + lane];
                _Float16 hs1e = hB[(size_t)s1 * 64 + lane];
                const h2* ap = easrt + (size_t)t * 8;
                h2 a0[8], a1[8];
#pragma unroll
                for (int k2 = 0; k2 < 8; ++k2) { a0[k2] = ap[k2]; a1[k2] = ap[8 + k2]; }
                __builtin_amdgcn_s_setprio(1);
                float hs0[NH], hs1[NH], p0[NH], p1[NH];
#pragma unroll
                for (int h = 0; h < 4; ++h) { hs0[h] = (float)hs0v[h]; hs1[h] = (float)hs1v[h]; }
                hs0[4] = (float)hs0e; hs1[4] = (float)hs1e;
#pragma unroll
                for (int h = 0; h < NH; ++h) {
                    float v0 = hs0[h] + hd[h];
                    float v1 = hs1[h] + hd[h];
#pragma unroll
                    for (int k2 = 0; k2 < 8; ++k2) {
                        v0 = __builtin_amdgcn_fdot2(a0[k2], we2[k2 * NH + h], v0, false);
                        v1 = __builtin_amdgcn_fdot2(a1[k2], we2[k2 * NH + h], v1, false);
                    }
                    p0[h] = fmaf(fabsf(v0), attc4[h], v0 * attc6[h]);
                    p1[h] = fmaf(fabsf(v1), attc4[h], v1 * attc6[h]);
                }
#pragma unroll
                for (int h = 0; h < NH; ++h) {
                    float pe0 = exp2f(wave_sum_all(p0[h]));
                    float pe1 = exp2f(wave_sum_all(p1[h]));
                    l[h] += pe0 + pe1;
                    acc[h] = fmaf(pe0, hs0[h], fmaf(pe1, hs1[h], acc[h]));
                }
                __builtin_amdgcn_s_setprio(0);
            }
            if (t < end) {
                int s0 = srcs[t];
                v4h hs0v = *(const v4h*)&hA[((size_t)s0 * 64 + lane) * 4];
                _Float16 hs0e = hB[(size_t)s0 * 64 + lane];
                const h2* ap = easrt + (size_t)t * 8;
                h2 a0[8];
#pragma unroll
                for (int k2 = 0; k2 < 8; ++k2) a0[k2] = ap[k2];
                float hs0[NH];
#pragma unroll
                for (int h = 0; h < 4; ++h) hs0[h] = (float)hs0v[h];
                hs0[4] = (float)hs0e;
#pragma unroll
                for (int h = 0; h < NH; ++h) {
                    float v0 = hs0[h] + hd[h];
#pragma unroll
                    for (int k2 = 0; k2 < 8; ++k2)
                        v0 = __builtin_amdgcn_fdot2(a0[k2], we2[k2 * NH + h], v0, false);
                    float pe0 = exp2f(wave_sum_all(fmaf(fabsf(v0), attc4[h], v0 * attc6[h])));
                    l[h] += pe0;
                    acc[h] = fmaf(pe0, hs0[h], acc[h]);
                }
            }
            float o = 0.f;
#pragma unroll
            for (int h = 0; h < NH; ++h) o += acc[h] / l[h];
            o = o * 0.2f + bc;
            o = o > 0.f ? o : expm1f(o);
            if (outF) outF[(size_t)i * NC + lane] = o;
            else      outH[(size_t)i * NC + lane] = (_Float16)o;
        }
    }
}

// ---------------- launch ----------------
extern "C" void kernel_launch(void* const* d_in, const int* in_sizes, int n_in,
                              void* d_out, int out_size, void* d_ws, size_t ws_size,
                              hipStream_t stream) {
    const float* x     = (const float*)d_in[0];
    const int*   ei    = (const int*)d_in[1];
    const float* ea    = (const float*)d_in[2];
    const float* W0    = (const float*)d_in[3];
    const float* b0    = (const float*)d_in[4];
    const float* We0   = (const float*)d_in[5];
    const float* att0  = (const float*)d_in[6];
    const float* bias0 = (const float*)d_in[7];
    const float* W12   = (const float*)d_in[8];
    const float* b12   = (const float*)d_in[9];
    const float* We12  = (const float*)d_in[10];
    const float* att12 = (const float*)d_in[11];
    const float* bias12= (const float*)d_in[12];

    int N = in_sizes[0] / 128;
    int E = in_sizes[1] / 2;
    int R = E + N;
    int numWin = (R + CH - 1) / CH;
    const int* srcArr = ei;
    const int* dstArr = ei + E;

    char* ws = (char*)d_ws;
    size_t off = 0;
    auto alloc = [&](size_t bytes) -> void* {
        void* p = ws + off;
        off = (off + bytes + 255) & ~(size_t)255;
        return p;
    };
    int*      cnt     = (int*)alloc((size_t)N * 4);
    int*      offsets = (int*)alloc((size_t)(N + 1) * 4);
    int*      cursor  = (int*)alloc((size_t)N * 4);
    int2*     recs    = (int2*)alloc((size_t)R * 8);
    int*      selfSlot= (int*)alloc((size_t)N * 4);
    _Float16* hbufA   = (_Float16*)alloc((size_t)N * 64 * 4 * 2); // [N][64][4] heads 0-3
    _Float16* hbufB   = (_Float16*)alloc((size_t)N * 64 * 2);     // [N][64]    head 4
    _Float16* acth    = (_Float16*)alloc((size_t)N * NC * 2);
    _Float16* Wth0    = (_Float16*)alloc((size_t)320 * 128 * 2);
    _Float16* Wth1    = (_Float16*)alloc((size_t)320 * 64 * 2);
    _Float16* Wth2    = (_Float16*)alloc((size_t)320 * 64 * 2);
    int*      winStart= (int*)alloc((size_t)(numWin + 1) * 4);
    h2*       easrt   = (h2*)alloc((size_t)R * 32);
    int*      srcs    = (int*)alloc((size_t)R * 4);

    (void)hipMemsetAsync(cnt, 0, (size_t)N * 4, stream);
    (void)hipMemsetAsync(winStart, 0x7f, (size_t)(numWin + 1) * 4, stream);
    count_kernel<<<(E + 255) / 256, 256, 0, stream>>>(dstArr, cnt, E);
    scan_kernel<<<1, 1024, 0, stream>>>(cnt, offsets, cursor, N);
    scatter_kernel<<<(E + N + 255) / 256, 256, 0, stream>>>(srcArr, dstArr, cursor, recs,
                                                            selfSlot, N, E);
    reorder_ea<<<((size_t)R * 8 + 255) / 256, 256, 0, stream>>>(recs, ea, easrt, srcs, R, E);
    loop_fill<<<((size_t)N * 8 + 255) / 256, 256, 0, stream>>>(offsets, selfSlot, easrt, N);
    win_start_kernel<<<(N + 255) / 256, 256, 0, stream>>>(offsets, winStart, N);
    transpose_w<<<(320 * 128 + 255) / 256, 256, 0, stream>>>(W0, Wth0, 128);
    transpose_w<<<(320 * 64 + 255) / 256, 256, 0, stream>>>(W12, Wth1, 64);
    transpose_w<<<(320 * 64 + 255) / 256, 256, 0, stream>>>(W12 + 64 * HC, Wth2, 64);

    float* dout = (float*)d_out;
    int gemmBlocks = (N / 16 + 3) / 4 + 1;
    int fusedBlocks = (numWin + 3) / 4;   // one window per wave

    const _Float16* Ahs[3] = {nullptr, acth, acth};
    const float*    Afs[3] = {x, nullptr, nullptr};
    const _Float16* Bts[3] = {Wth0, Wth1, Wth2};
    int Ks[3] = {128, 64, 64};
    const float* bs[3]   = {b0, b12, b12 + HC};
    const float* Wes[3]  = {We0, We12, We12 + ED * HC};
    const float* atts[3] = {att0, att12, att12 + NH * NC};
    const float* bis[3]  = {bias0, bias12, bias12 + NC};
    for (int layer = 0; layer < 3; ++layer) {
        gemm_mfma<<<gemmBlocks, 256, 0, stream>>>(Ahs[layer], Afs[layer], Bts[layer], bs[layer],
                                                  hbufA, hbufB, N, Ks[layer]);
        gat_fused<<<fusedBlocks, 256, 0, stream>>>(hbufA, hbufB, offsets, srcs, easrt, winStart,
                                                   Wes[layer], atts[layer], bis[layer],
                                                   acth, (layer == 2) ? dout : nullptr, N, R);
    }
}